// Round 1
// baseline (457.609 us; speedup 1.0000x reference)
//
#include <hip/hip_runtime.h>

// F0 extraction via autocorrelation argmax.
// Reference constants (resolved):
//   SR=16000, HOP=256, FRAME_LEN=512, pad=256, T=163840, B=64
//   n_frames=641, lags p in [32,256) -> 224 lags
// Normalization is a per-frame positive scalar -> does not affect argmax.
// Accumulate raw autocorrelation in fp64 so argmax matches the exact result.

#define SR_F 16000.0f
#define HOP 256
#define FRAME_LEN 512
#define PAD 256
#define T_LEN 163840
#define N_FRAMES 641
#define MIN_PERIOD 32
#define LAG_END 256
#define N_LAGS (LAG_END - MIN_PERIOD) // 224

__global__ __launch_bounds__(256) void f0_kernel(const float* __restrict__ wav,
                                                 float* __restrict__ out) {
    __shared__ float s[FRAME_LEN];
    __shared__ double red_v[256];
    __shared__ int red_i[256];

    const int bf = blockIdx.x;             // b * N_FRAMES + f
    const int b  = bf / N_FRAMES;
    const int f  = bf - b * N_FRAMES;
    const float* __restrict__ x = wav + (size_t)b * T_LEN;
    const int tid = threadIdx.x;

    // Load 512-sample frame with reflect padding (only frames 0 / 640 reflect).
    const int base = f * HOP - PAD;
    for (int t = tid; t < FRAME_LEN; t += 256) {
        int idx = base + t;
        if (idx < 0) idx = -idx;                       // reflect left (excl. edge)
        if (idx >= T_LEN) idx = 2 * (T_LEN - 1) - idx; // reflect right
        s[t] = x[idx];
    }
    __syncthreads();

    // Thread tid < 224 computes lag p = 32 + tid.
    double acc = -__builtin_inf();
    int lag = 0x7fffffff;
    if (tid < N_LAGS) {
        const int p = MIN_PERIOD + tid;
        double a = 0.0;
        const int n = FRAME_LEN - p; // zero-padded tail contributes nothing
        for (int t = 0; t < n; ++t)
            a = fma((double)s[t], (double)s[t + p], a);
        acc = a;
        lag = p;
    }

    red_v[tid] = acc;
    red_i[tid] = lag;
    __syncthreads();

    // Tree argmax with first-index (lowest lag) tie-break, matching jnp.argmax.
    for (int stride = 128; stride > 0; stride >>= 1) {
        if (tid < stride) {
            double v1 = red_v[tid], v2 = red_v[tid + stride];
            int    i1 = red_i[tid], i2 = red_i[tid + stride];
            if (v2 > v1 || (v2 == v1 && i2 < i1)) {
                red_v[tid] = v2;
                red_i[tid] = i2;
            }
        }
        __syncthreads();
    }

    if (tid == 0) {
        float period = (float)red_i[0];
        float f0 = SR_F / (period + 1e-8f);
        f0 = fminf(fmaxf(f0, 50.0f), 500.0f);
        out[bf] = f0;
    }
}

extern "C" void kernel_launch(void* const* d_in, const int* in_sizes, int n_in,
                              void* d_out, int out_size, void* d_ws, size_t ws_size,
                              hipStream_t stream) {
    const float* wav = (const float*)d_in[0]; // (64, 1, 163840) fp32
    float* out = (float*)d_out;               // (64, 641) fp32
    const int n_blocks = 64 * N_FRAMES;       // 41024
    f0_kernel<<<n_blocks, 256, 0, stream>>>(wav, out);
}

// Round 2
// 261.441 us; speedup vs baseline: 1.7503x; 1.7503x over previous
//
#include <hip/hip_runtime.h>

// F0 extraction via autocorrelation argmax — round 2: register-tiled fp64.
//   SR=16000, HOP=256, FRAME_LEN=512, pad=256, T=163840, B=64
//   n_frames=641, lags p in [32,256) -> 224 lags
// Per-frame normalization is a positive scalar -> argmax unaffected; we take
// argmax of the raw autocorrelation, accumulated in fp64 (exact products of
// fp32 inputs) so the argmax matches the numpy reference exactly.
//
// Work layout per block (one block per (batch,frame)):
//   224 active threads = 28 lag-groups (8 consecutive lags each) x 8 t-segments.
//   Each thread iterates 8-wide t-chunks (strided by segment), computing an
//   8-lag x 8-t register tile per iteration:
//     2x ds_read_b128 (a = s[t..t+7]) + 4x ds_read_b128 (w = s[t+p0..t+p0+15])
//     -> 64 v_fma_f64.
//   LDS frame is zero-padded to 640 so tail reads contribute 0 (identical to
//   the reference's zero padding) — no bounds checks in the hot loop.

#define SR_F 16000.0f
#define HOP 256
#define FRAME_LEN 512
#define PAD 256
#define T_LEN 163840
#define N_FRAMES 641
#define MIN_PERIOD 32
#define N_LAGS 224      // lags 32..255
#define S_LEN 640       // 512 data + 128 zero pad (covers max window index ~596)
#define NSEGS 8

__global__ __launch_bounds__(256) void f0_kernel(const float* __restrict__ wav,
                                                 float* __restrict__ out) {
    __shared__ float  s[S_LEN];
    __shared__ double red[N_LAGS * NSEGS];  // partial sums [lag][seg]
    __shared__ double red_v[256];
    __shared__ int    red_i[256];

    const int bf = blockIdx.x;             // b * N_FRAMES + f
    const int b  = bf / N_FRAMES;
    const int f  = bf - b * N_FRAMES;
    const float* __restrict__ x = wav + (size_t)b * T_LEN;
    const int tid = threadIdx.x;

    // Load 512-sample frame with reflect padding (only frames 0 / 640 reflect).
    const int base = f * HOP - PAD;
    for (int t = tid; t < FRAME_LEN; t += 256) {
        int idx = base + t;
        if (idx < 0) idx = -idx;                       // reflect left
        if (idx >= T_LEN) idx = 2 * (T_LEN - 1) - idx; // reflect right
        s[t] = x[idx];
    }
    if (tid < (S_LEN - FRAME_LEN)) s[FRAME_LEN + tid] = 0.0f;  // zero pad tail
    __syncthreads();

    const int g   = tid >> 3;             // lag group: lags 32+8g .. 39+8g
    const int seg = tid & 7;              // t-segment
    const int p0  = MIN_PERIOD + (g << 3);

    double acc[8];
    #pragma unroll
    for (int j = 0; j < 8; ++j) acc[j] = 0.0;

    if (tid < N_LAGS) {
        const int n8 = (FRAME_LEN - p0 + 7) >> 3;   // # of 8-elem t-chunks
        const float4* s4 = (const float4*)s;
        for (int ch = seg; ch < n8; ch += NSEGS) {
            const int t = ch << 3;
            // a = s[t .. t+7]
            const float4 a0 = s4[t >> 2];
            const float4 a1 = s4[(t >> 2) + 1];
            // w = s[t+p0 .. t+p0+15]  (w[15] unused, DCE'd)
            const int wq = (t + p0) >> 2;
            const float4 w0 = s4[wq];
            const float4 w1 = s4[wq + 1];
            const float4 w2 = s4[wq + 2];
            const float4 w3 = s4[wq + 3];

            const double a[8] = {(double)a0.x, (double)a0.y, (double)a0.z, (double)a0.w,
                                 (double)a1.x, (double)a1.y, (double)a1.z, (double)a1.w};
            const double w[16] = {(double)w0.x, (double)w0.y, (double)w0.z, (double)w0.w,
                                  (double)w1.x, (double)w1.y, (double)w1.z, (double)w1.w,
                                  (double)w2.x, (double)w2.y, (double)w2.z, (double)w2.w,
                                  (double)w3.x, (double)w3.y, (double)w3.z, (double)w3.w};
            #pragma unroll
            for (int j = 0; j < 8; ++j) {
                #pragma unroll
                for (int i = 0; i < 8; ++i)
                    acc[j] = fma(a[i], w[i + j], acc[j]);
            }
        }
        #pragma unroll
        for (int j = 0; j < 8; ++j)
            red[(((g << 3) + j) << 3) + seg] = acc[j];
    }
    __syncthreads();

    // Sum the 8 segment partials per lag (fixed order), then argmax tree.
    double v = -__builtin_inf();
    int lagidx = 0x7fffffff;
    if (tid < N_LAGS) {
        const double* r = &red[tid << 3];
        v = ((r[0] + r[1]) + (r[2] + r[3])) + ((r[4] + r[5]) + (r[6] + r[7]));
        lagidx = tid;
    }
    red_v[tid] = v;
    red_i[tid] = lagidx;
    __syncthreads();

    // First-index (lowest-lag) tie-break, matching jnp.argmax.
    for (int stride = 128; stride > 0; stride >>= 1) {
        if (tid < stride) {
            double v1 = red_v[tid], v2 = red_v[tid + stride];
            int    i1 = red_i[tid], i2 = red_i[tid + stride];
            if (v2 > v1 || (v2 == v1 && i2 < i1)) {
                red_v[tid] = v2;
                red_i[tid] = i2;
            }
        }
        __syncthreads();
    }

    if (tid == 0) {
        float period = (float)(red_i[0] + MIN_PERIOD);
        float f0 = SR_F / (period + 1e-8f);
        f0 = fminf(fmaxf(f0, 50.0f), 500.0f);
        out[bf] = f0;
    }
}

extern "C" void kernel_launch(void* const* d_in, const int* in_sizes, int n_in,
                              void* d_out, int out_size, void* d_ws, size_t ws_size,
                              hipStream_t stream) {
    const float* wav = (const float*)d_in[0]; // (64, 1, 163840) fp32
    float* out = (float*)d_out;               // (64, 641) fp32
    const int n_blocks = 64 * N_FRAMES;       // 41024
    f0_kernel<<<n_blocks, 256, 0, stream>>>(wav, out);
}